// Round 4
// baseline (101.400 us; speedup 1.0000x reference)
//
#include <hip/hip_runtime.h>
#include <hip/hip_bf16.h>

// B=1, S=4096, D=4096, O=4096
//   q = fake-quant(x) per row (int8 levels, scale = 127/max(|x|,1e-5))
//   out[s,o] = (sum_d qi[s,d]*W[o,d]) * rscale[s]/ws + bias[o]/ws
// qi in [-128,127], W in {-1,0,1}: i8 MFMA with i32 accum is EXACT (|sum|<2^19).
//
// GEMM: 256x256 tile, BK=64, ring-4 LDS pipeline, counted vmcnt(8),
// 1 barrier per K-tile, conflict-free swizzled LDS (R2/R3-verified),
// mfma_i32_32x32x32_i8 (2x work/instr vs 16x16x64, +12% pipe rate),
// 2 half-K phases per tile with setprio(1) around each MFMA cluster (T5).

#define SEQ  4096
#define DIM  4096
#define OUTD 4096

typedef int i32x4 __attribute__((ext_vector_type(4)));
typedef int i32x16 __attribute__((ext_vector_type(16)));
typedef unsigned char u8;

__device__ __forceinline__ void gload16(const void* g, void* lds) {
    __builtin_amdgcn_global_load_lds(
        (const __attribute__((address_space(1))) void*)g,
        (__attribute__((address_space(3))) void*)lds, 16, 0, 0);
}

// LDS layout per slot (per matrix): 256 rows x 64B (i8), 128 row-pairs of 128B.
// Element (r, 16B-quarter kq) at byte:
//   (r>>1)*128 + ((((r&1)<<6) | (kq<<4)) ^ (((r>>1)&3)<<4))
// Verified conflict-free on ds_read_b128 (R2/R3: SQ_LDS_BANK_CONFLICT == 0).
__device__ __forceinline__ int ldsoff(int r, int kq) {
    const int rp = r >> 1;
    const int w = (((r & 1) << 6) | (kq << 4)) ^ ((rp & 3) << 4);
    return rp * 128 + w;
}

// ---------------- Kernel 1: per-row activation fake-quant -> i8 qi ----------------
__global__ __launch_bounds__(256) void quant_kernel(
    const float* __restrict__ x, char* __restrict__ q, float* __restrict__ rscale) {
    const int row = blockIdx.x;
    const int t = threadIdx.x;
    const int lane = t & 63, wave = t >> 6;
    const float4* xr = (const float4*)(x + (size_t)row * DIM);

    float4 r[4];
    float m = 0.0f;
#pragma unroll
    for (int i = 0; i < 4; ++i) {
        r[i] = xr[t + 256 * i];
        m = fmaxf(m, fmaxf(fmaxf(fabsf(r[i].x), fabsf(r[i].y)),
                           fmaxf(fabsf(r[i].z), fabsf(r[i].w))));
    }
#pragma unroll
    for (int off = 32; off > 0; off >>= 1)
        m = fmaxf(m, __shfl_xor(m, off, 64));
    __shared__ float red[4];
    if (lane == 0) red[wave] = m;
    __syncthreads();
    const float amax = fmaxf(fmaxf(red[0], red[1]), fmaxf(red[2], red[3]));
    const float scale = 127.0f / fmaxf(amax, 1e-5f);
    if (t == 0) rscale[row] = 1.0f / scale;

    char4* qr = (char4*)(q + (size_t)row * DIM);
#pragma unroll
    for (int i = 0; i < 4; ++i) {
        float q0 = fminf(127.0f, fmaxf(-128.0f, rintf(r[i].x * scale)));
        float q1 = fminf(127.0f, fmaxf(-128.0f, rintf(r[i].y * scale)));
        float q2 = fminf(127.0f, fmaxf(-128.0f, rintf(r[i].z * scale)));
        float q3 = fminf(127.0f, fmaxf(-128.0f, rintf(r[i].w * scale)));
        char4 o;
        o.x = (signed char)q0; o.y = (signed char)q1;
        o.z = (signed char)q2; o.w = (signed char)q3;
        qr[t + 256 * i] = o;
    }
}

// ---------------- Kernel 2: W fp32 {-1,0,1} -> i8 ----------------
__global__ __launch_bounds__(256) void wconv_kernel(
    const float4* __restrict__ W4, char4* __restrict__ Wb4, int n4) {
    int i = blockIdx.x * blockDim.x + threadIdx.x;
    const int stride = gridDim.x * blockDim.x;
    for (; i < n4; i += stride) {
        float4 w = W4[i];
        char4 o;
        o.x = (signed char)w.x; o.y = (signed char)w.y;
        o.z = (signed char)w.z; o.w = (signed char)w.w;
        Wb4[i] = o;
    }
}

// ---------------- Kernel 3: ring-4 pipelined i8 GEMM (32x32x32), fused epilogue ----
__global__ __launch_bounds__(512, 2) void gemm_kernel(
    const u8* __restrict__ A, const u8* __restrict__ B,
    const float* __restrict__ rscale, const float* __restrict__ bias,
    const float* __restrict__ wscale, float* __restrict__ out) {
    __shared__ __align__(16) u8 As[4 * 16384];   // 4 slots x 16KB
    __shared__ __align__(16) u8 Bs[4 * 16384];
    const int tid = threadIdx.x;
    const int lane = tid & 63, wave = tid >> 6;
    const int wr = wave >> 2, wc = wave & 3;       // 2 x 4 waves, 128x64 per wave
    const int cl = lane & 31;                      // frag row/col lane index
    const int kh = lane >> 5;                      // K-half within 32B K-step

    // bijective XCD swizzle (256 % 8 == 0)
    const int bid = blockIdx.x;
    const int swz = (bid & 7) * 32 + (bid >> 3);
    const int brow = swz >> 4, bcol = swz & 15;

    // staging: LDS dest linear (thread t -> bytes t*16 of each 8KB chunk);
    // inverse swizzle applied to the GLOBAL source (involution).
    const int v = (tid & 7) ^ ((tid >> 3) & 3);
    const int kb = (v & 3) * 16;                   // byte offset within 64B row
    const int r0 = ((tid >> 3) << 1) + (v >> 2);   // chunk0 tile-row
    const u8* gA0 = A + (size_t)(brow * 256 + r0) * DIM + kb;
    const u8* gA1 = A + (size_t)(brow * 256 + 128 + r0) * DIM + kb;
    const u8* gB0 = B + (size_t)(bcol * 256 + r0) * DIM + kb;
    const u8* gB1 = B + (size_t)(bcol * 256 + 128 + r0) * DIM + kb;
    u8* lA0 = &As[tid * 16];
    u8* lA1 = &As[8192 + tid * 16];
    u8* lB0 = &Bs[tid * 16];
    u8* lB1 = &Bs[8192 + tid * 16];

#define STAGE(T, S) do { const int _k = (T) * 64;          \
        gload16(gA0 + _k, lA0 + (S) * 16384);              \
        gload16(gA1 + _k, lA1 + (S) * 16384);              \
        gload16(gB0 + _k, lB0 + (S) * 16384);              \
        gload16(gB1 + _k, lB1 + (S) * 16384); } while (0)

    // fragment LDS offsets: frag row = base + cl, 16B quarter = s*2 + kh
    int aoff[4][2], boff[2][2];
#pragma unroll
    for (int m = 0; m < 4; ++m)
#pragma unroll
        for (int s = 0; s < 2; ++s)
            aoff[m][s] = ldsoff(wr * 128 + m * 32 + cl, s * 2 + kh);
#pragma unroll
    for (int n = 0; n < 2; ++n)
#pragma unroll
        for (int s = 0; s < 2; ++s)
            boff[n][s] = ldsoff(wc * 64 + n * 32 + cl, s * 2 + kh);

    i32x16 acc[4][2] = {};

#define LOADFRAG(S, s, af, bfv)                                                \
    _Pragma("unroll")                                                          \
    for (int m = 0; m < 4; ++m)                                                \
        af[m] = *(const i32x4*)&As[(S) * 16384 + aoff[m][s]];                  \
    _Pragma("unroll")                                                          \
    for (int n = 0; n < 2; ++n)                                                \
        bfv[n] = *(const i32x4*)&Bs[(S) * 16384 + boff[n][s]];

#define MFMA8(af, bfv)                                                         \
    __builtin_amdgcn_s_setprio(1);                                             \
    _Pragma("unroll")                                                          \
    for (int m = 0; m < 4; ++m)                                                \
        _Pragma("unroll")                                                      \
        for (int n = 0; n < 2; ++n)                                            \
            acc[m][n] = __builtin_amdgcn_mfma_i32_32x32x32_i8(                 \
                af[m], bfv[n], acc[m][n], 0, 0, 0);                            \
    __builtin_amdgcn_s_setprio(0);

#define VMW(N) asm volatile("s_waitcnt vmcnt(" #N ")" ::: "memory")
#define BAR()  do { asm volatile("" ::: "memory");                             \
                    __builtin_amdgcn_s_barrier();                              \
                    asm volatile("" ::: "memory"); } while (0)

// full tile with prefetch stage into slot (S+3)&3
#define TILE_S(S, T) do {                                                      \
        VMW(8); BAR();                                                         \
        { i32x4 af[4], bfv[2];                                                 \
          LOADFRAG(S, 0, af, bfv);                                             \
          STAGE(T, ((S) + 3) & 3);                                             \
          MFMA8(af, bfv); }                                                    \
        { i32x4 af[4], bfv[2];                                                 \
          LOADFRAG(S, 1, af, bfv);                                             \
          MFMA8(af, bfv); }                                                    \
    } while (0)

// tail tile, no stage
#define TILE_N(S) do {                                                         \
        { i32x4 af[4], bfv[2];                                                 \
          LOADFRAG(S, 0, af, bfv);                                             \
          MFMA8(af, bfv); }                                                    \
        { i32x4 af[4], bfv[2];                                                 \
          LOADFRAG(S, 1, af, bfv);                                             \
          MFMA8(af, bfv); }                                                    \
    } while (0)

    // 64 K-tiles of BK=64. Prologue: tiles 0..2 in flight.
    STAGE(0, 0); STAGE(1, 1); STAGE(2, 2);

    for (int tb = 0; tb < 15; ++tb) {
        const int t = tb * 4;
        TILE_S(0, t + 3);
        TILE_S(1, t + 4);
        TILE_S(2, t + 5);
        TILE_S(3, t + 6);
    }
    // tail: tiles 60..63
    TILE_S(0, 63);
    VMW(8); BAR(); TILE_N(1);
    VMW(4); BAR(); TILE_N(2);
    VMW(0); BAR(); TILE_N(3);

    // epilogue: 32x32 C/D layout col=lane&31, row=(reg&3)+8*(reg>>2)+4*(lane>>5)
    const float invws = 1.0f / wscale[0];
    const int rr0 = brow * 256 + wr * 128 + kh * 4;
    const int c0 = bcol * 256 + wc * 64 + cl;
    float bv[2];
#pragma unroll
    for (int n = 0; n < 2; ++n) bv[n] = bias[c0 + n * 32] * invws;
#pragma unroll
    for (int m = 0; m < 4; ++m) {
#pragma unroll
        for (int qg = 0; qg < 4; ++qg) {
#pragma unroll
            for (int j = 0; j < 4; ++j) {
                const int r = rr0 + m * 32 + qg * 8 + j;
                const int reg = qg * 4 + j;
                const float rs = rscale[r] * invws;
                float* orow = out + (size_t)r * OUTD + c0;
#pragma unroll
                for (int n = 0; n < 2; ++n)
                    orow[n * 32] = (float)acc[m][n][reg] * rs + bv[n];
            }
        }
    }
#undef STAGE
#undef LOADFRAG
#undef MFMA8
#undef VMW
#undef BAR
#undef TILE_S
#undef TILE_N
}

extern "C" void kernel_launch(void* const* d_in, const int* in_sizes, int n_in,
                              void* d_out, int out_size, void* d_ws, size_t ws_size,
                              hipStream_t stream) {
    const float* x      = (const float*)d_in[0];
    const float* W      = (const float*)d_in[1];
    const float* bias   = (const float*)d_in[2];
    const float* wscale = (const float*)d_in[3];
    float* out = (float*)d_out;

    char* ws = (char*)d_ws;
    char* q_i8 = ws;                                   // 16 MB
    char* w_i8 = ws + (size_t)16777216;                // 16 MB
    float* rscale = (float*)(ws + (size_t)33554432);   // 16 KB

    quant_kernel<<<SEQ, 256, 0, stream>>>(x, q_i8, rscale);
    wconv_kernel<<<4096, 256, 0, stream>>>((const float4*)W, (char4*)w_i8,
                                           (OUTD * DIM) / 4);
    gemm_kernel<<<256, 512, 0, stream>>>((const u8*)q_i8, (const u8*)w_i8,
                                         rscale, bias, wscale, out);
}

// Round 5
// 95.082 us; speedup vs baseline: 1.0664x; 1.0664x over previous
//
#include <hip/hip_runtime.h>
#include <hip/hip_bf16.h>

// B=1, S=4096, D=4096, O=4096
//   q = fake-quant(x) per row (int8 levels, scale = 127/max(|x|,1e-5))
//   out[s,o] = (sum_d qi[s,d]*W[o,d]) * rscale[s]/ws + bias[o]/ws
// qi in [-128,127], W in {-1,0,1}: i8 MFMA with i32 accum is EXACT (|sum|<2^19).
//
// GEMM: R3-verified geometry (256x256 tile, BK=64, mfma_i32_16x16x64_i8,
// conflict-free swizzled LDS, ring-4 + counted vmcnt(8), 1 barrier/tile)
// + NEW this round (isolated variable): 2-phase M-split per tile with
// setprio(1) around each MFMA cluster (T5 needs phase diversity, m218b).

#define SEQ  4096
#define DIM  4096
#define OUTD 4096

typedef int i32x4 __attribute__((ext_vector_type(4)));
typedef unsigned char u8;

__device__ __forceinline__ void gload16(const void* g, void* lds) {
    __builtin_amdgcn_global_load_lds(
        (const __attribute__((address_space(1))) void*)g,
        (__attribute__((address_space(3))) void*)lds, 16, 0, 0);
}

// LDS layout per slot (per matrix): 256 rows x 64B (i8), 128 row-pairs of 128B.
// Element (r, 16B-quarter kq) at byte:
//   (r>>1)*128 + ((((r&1)<<6) | (kq<<4)) ^ (((r>>1)&3)<<4))
// Verified conflict-free on ds_read_b128 with the (fr=lane&15, kq=lane>>4)
// fragment pattern (R2/R3: SQ_LDS_BANK_CONFLICT == 0).
__device__ __forceinline__ int ldsoff(int r, int kq) {
    const int rp = r >> 1;
    const int w = (((r & 1) << 6) | (kq << 4)) ^ ((rp & 3) << 4);
    return rp * 128 + w;
}

// ---------------- Kernel 1: per-row activation fake-quant -> i8 qi ----------------
__global__ __launch_bounds__(256) void quant_kernel(
    const float* __restrict__ x, char* __restrict__ q, float* __restrict__ rscale) {
    const int row = blockIdx.x;
    const int t = threadIdx.x;
    const int lane = t & 63, wave = t >> 6;
    const float4* xr = (const float4*)(x + (size_t)row * DIM);

    float4 r[4];
    float m = 0.0f;
#pragma unroll
    for (int i = 0; i < 4; ++i) {
        r[i] = xr[t + 256 * i];
        m = fmaxf(m, fmaxf(fmaxf(fabsf(r[i].x), fabsf(r[i].y)),
                           fmaxf(fabsf(r[i].z), fabsf(r[i].w))));
    }
#pragma unroll
    for (int off = 32; off > 0; off >>= 1)
        m = fmaxf(m, __shfl_xor(m, off, 64));
    __shared__ float red[4];
    if (lane == 0) red[wave] = m;
    __syncthreads();
    const float amax = fmaxf(fmaxf(red[0], red[1]), fmaxf(red[2], red[3]));
    const float scale = 127.0f / fmaxf(amax, 1e-5f);
    if (t == 0) rscale[row] = 1.0f / scale;

    char4* qr = (char4*)(q + (size_t)row * DIM);
#pragma unroll
    for (int i = 0; i < 4; ++i) {
        float q0 = fminf(127.0f, fmaxf(-128.0f, rintf(r[i].x * scale)));
        float q1 = fminf(127.0f, fmaxf(-128.0f, rintf(r[i].y * scale)));
        float q2 = fminf(127.0f, fmaxf(-128.0f, rintf(r[i].z * scale)));
        float q3 = fminf(127.0f, fmaxf(-128.0f, rintf(r[i].w * scale)));
        char4 o;
        o.x = (signed char)q0; o.y = (signed char)q1;
        o.z = (signed char)q2; o.w = (signed char)q3;
        qr[t + 256 * i] = o;
    }
}

// ---------------- Kernel 2: W fp32 {-1,0,1} -> i8 ----------------
__global__ __launch_bounds__(256) void wconv_kernel(
    const float4* __restrict__ W4, char4* __restrict__ Wb4, int n4) {
    int i = blockIdx.x * blockDim.x + threadIdx.x;
    const int stride = gridDim.x * blockDim.x;
    for (; i < n4; i += stride) {
        float4 w = W4[i];
        char4 o;
        o.x = (signed char)w.x; o.y = (signed char)w.y;
        o.z = (signed char)w.z; o.w = (signed char)w.w;
        Wb4[i] = o;
    }
}

// ---------------- Kernel 3: ring-4 pipelined i8 GEMM, 2-phase tiles ----------------
__global__ __launch_bounds__(512, 2) void gemm_kernel(
    const u8* __restrict__ A, const u8* __restrict__ B,
    const float* __restrict__ rscale, const float* __restrict__ bias,
    const float* __restrict__ wscale, float* __restrict__ out) {
    __shared__ __align__(16) u8 As[4 * 16384];   // 4 slots x 16KB
    __shared__ __align__(16) u8 Bs[4 * 16384];
    const int tid = threadIdx.x;
    const int lane = tid & 63, wave = tid >> 6;
    const int wr = wave >> 2, wc = wave & 3;       // 2 x 4 waves, 128x64 per wave
    const int fr = lane & 15, kq = lane >> 4;

    // bijective XCD swizzle (256 % 8 == 0)
    const int bid = blockIdx.x;
    const int swz = (bid & 7) * 32 + (bid >> 3);
    const int brow = swz >> 4, bcol = swz & 15;

    // staging: LDS dest linear (thread t -> bytes t*16 of each 8KB chunk);
    // inverse swizzle applied to the GLOBAL source (involution).
    const int v = (tid & 7) ^ ((tid >> 3) & 3);
    const int kb = (v & 3) * 16;                   // byte offset within 64B row
    const int r0 = ((tid >> 3) << 1) + (v >> 2);   // chunk0 tile-row
    const u8* gA0 = A + (size_t)(brow * 256 + r0) * DIM + kb;
    const u8* gA1 = A + (size_t)(brow * 256 + 128 + r0) * DIM + kb;
    const u8* gB0 = B + (size_t)(bcol * 256 + r0) * DIM + kb;
    const u8* gB1 = B + (size_t)(bcol * 256 + 128 + r0) * DIM + kb;
    u8* lA0 = &As[tid * 16];
    u8* lA1 = &As[8192 + tid * 16];
    u8* lB0 = &Bs[tid * 16];
    u8* lB1 = &Bs[8192 + tid * 16];

#define STAGE(T, S) do { const int _k = (T) * 64;          \
        gload16(gA0 + _k, lA0 + (S) * 16384);              \
        gload16(gA1 + _k, lA1 + (S) * 16384);              \
        gload16(gB0 + _k, lB0 + (S) * 16384);              \
        gload16(gB1 + _k, lB1 + (S) * 16384); } while (0)

    int aoff[8], boff[4];
#pragma unroll
    for (int m = 0; m < 8; ++m) aoff[m] = ldsoff(wr * 128 + m * 16 + fr, kq);
#pragma unroll
    for (int n = 0; n < 4; ++n) boff[n] = ldsoff(wc * 64 + n * 16 + fr, kq);

    i32x4 acc[8][4] = {};

#define VMW(N) asm volatile("s_waitcnt vmcnt(" #N ")" ::: "memory")
#define BAR()  do { asm volatile("" ::: "memory");                             \
                    __builtin_amdgcn_s_barrier();                              \
                    asm volatile("" ::: "memory"); } while (0)

// Phase 0: A m0-3 + all B reads, STAGE prefetch, 16 MFMAs under setprio.
// Phase 1: A m4-7 reads, 16 MFMAs under setprio.
#define TILE_BODY(S, DO_STAGE, T) do {                                         \
        { i32x4 af[4], bfv[4];                                                 \
          _Pragma("unroll")                                                    \
          for (int m = 0; m < 4; ++m)                                          \
              af[m] = *(const i32x4*)&As[(S) * 16384 + aoff[m]];               \
          _Pragma("unroll")                                                    \
          for (int n = 0; n < 4; ++n)                                          \
              bfv[n] = *(const i32x4*)&Bs[(S) * 16384 + boff[n]];              \
          if (DO_STAGE) STAGE(T, ((S) + 3) & 3);                               \
          __builtin_amdgcn_s_setprio(1);                                       \
          _Pragma("unroll")                                                    \
          for (int m = 0; m < 4; ++m)                                          \
              _Pragma("unroll")                                                \
              for (int n = 0; n < 4; ++n)                                      \
                  acc[m][n] = __builtin_amdgcn_mfma_i32_16x16x64_i8(           \
                      af[m], bfv[n], acc[m][n], 0, 0, 0);                      \
          __builtin_amdgcn_s_setprio(0);                                       \
          _Pragma("unroll")                                                    \
          for (int m = 0; m < 4; ++m)                                          \
              af[m] = *(const i32x4*)&As[(S) * 16384 + aoff[4 + m]];           \
          __builtin_amdgcn_s_setprio(1);                                       \
          _Pragma("unroll")                                                    \
          for (int m = 0; m < 4; ++m)                                          \
              _Pragma("unroll")                                                \
              for (int n = 0; n < 4; ++n)                                      \
                  acc[4 + m][n] = __builtin_amdgcn_mfma_i32_16x16x64_i8(       \
                      af[m], bfv[n], acc[4 + m][n], 0, 0, 0);                  \
          __builtin_amdgcn_s_setprio(0); }                                     \
    } while (0)

    // 64 K-tiles of BK=64. Prologue: tiles 0..2 in flight.
    STAGE(0, 0); STAGE(1, 1); STAGE(2, 2);

    for (int tb = 0; tb < 15; ++tb) {
        const int t = tb * 4;
        VMW(8); BAR(); TILE_BODY(0, 1, t + 3);
        VMW(8); BAR(); TILE_BODY(1, 1, t + 4);
        VMW(8); BAR(); TILE_BODY(2, 1, t + 5);
        VMW(8); BAR(); TILE_BODY(3, 1, t + 6);
    }
    // tail: tiles 60..63
    VMW(8); BAR(); TILE_BODY(0, 1, 63);
    VMW(8); BAR(); TILE_BODY(1, 0, 0);
    VMW(4); BAR(); TILE_BODY(2, 0, 0);
    VMW(0); BAR(); TILE_BODY(3, 0, 0);

    // epilogue: C/D layout col=lane&15, row=(lane>>4)*4+j (dtype-independent)
    const float invws = 1.0f / wscale[0];
    const int rr0 = brow * 256 + wr * 128 + (kq << 2);
    const int c0 = bcol * 256 + wc * 64 + fr;
    float bv[4];
#pragma unroll
    for (int n = 0; n < 4; ++n) bv[n] = bias[c0 + n * 16] * invws;
#pragma unroll
    for (int m = 0; m < 8; ++m) {
#pragma unroll
        for (int j = 0; j < 4; ++j) {
            const int r = rr0 + m * 16 + j;
            const float rs = rscale[r] * invws;
            float* orow = out + (size_t)r * OUTD + c0;
#pragma unroll
            for (int n = 0; n < 4; ++n)
                orow[n * 16] = (float)acc[m][n][j] * rs + bv[n];
        }
    }
#undef STAGE
#undef VMW
#undef BAR
#undef TILE_BODY
}

extern "C" void kernel_launch(void* const* d_in, const int* in_sizes, int n_in,
                              void* d_out, int out_size, void* d_ws, size_t ws_size,
                              hipStream_t stream) {
    const float* x      = (const float*)d_in[0];
    const float* W      = (const float*)d_in[1];
    const float* bias   = (const float*)d_in[2];
    const float* wscale = (const float*)d_in[3];
    float* out = (float*)d_out;

    char* ws = (char*)d_ws;
    char* q_i8 = ws;                                   // 16 MB
    char* w_i8 = ws + (size_t)16777216;                // 16 MB
    float* rscale = (float*)(ws + (size_t)33554432);   // 16 KB

    quant_kernel<<<SEQ, 256, 0, stream>>>(x, q_i8, rscale);
    wconv_kernel<<<4096, 256, 0, stream>>>((const float4*)W, (char4*)w_i8,
                                           (OUTD * DIM) / 4);
    gemm_kernel<<<256, 512, 0, stream>>>((const u8*)q_i8, (const u8*)w_i8,
                                         rscale, bias, wscale, out);
}